// Round 1
// baseline (109.848 us; speedup 1.0000x reference)
//
#include <hip/hip_runtime.h>
#include <hip/hip_bf16.h>
#include <math.h>

#define KL 64      // locations
#define NT 8192    // time steps
#define MF 8       // covariate features
#define DD 32      // memory depth
#define WIN 64     // 2*DD window taps
#define HD 20      // hidden dim
#define HP 32      // hidden padded to 2 MFMA N-tiles
#define KF 512     // 2*DD*MF = GEMM K
#define NB 256     // n-rows per block
#define NXB (NT / NB)          // 32 n-tiles
#define NBLK (NXB * KL)        // 2048 mlp blocks

typedef __attribute__((ext_vector_type(8))) short bf16x8;
typedef __attribute__((ext_vector_type(4))) float f32x4;

__device__ __forceinline__ float softplus_f(float x) {
    float e = __expf(-fabsf(x));
    return fmaxf(x, 0.0f) + __logf(1.0f + e);
}
__device__ __forceinline__ short f2bf(float x) {
    __hip_bfloat16 h = __float2bfloat16(x);
    return *reinterpret_cast<short*>(&h);
}

// ---- Kernel 1 (tiny): pack W1 -> bf16 [HP][KF], pad b1/W2 to HP ----
__global__ __launch_bounds__(256)
void pack_kernel(const float* __restrict__ W1, const float* __restrict__ b1,
                 const float* __restrict__ W2, short* __restrict__ W1b,
                 float* __restrict__ b1p, float* __restrict__ W2p) {
    int t = blockIdx.x * 256 + threadIdx.x;     // grid 16 -> 4096 threads
    #pragma unroll
    for (int i = 0; i < 4; ++i) {
        int idx = t + i * 4096;                 // HP*KF = 16384
        int o = idx >> 9;                       // KF = 512
        int f = idx & (KF - 1);
        W1b[idx] = (o < HD) ? f2bf(W1[o * KF + f]) : (short)0;
    }
    if (blockIdx.x == 0 && threadIdx.x < HP) {
        b1p[threadIdx.x] = (threadIdx.x < HD) ? b1[threadIdx.x] : 0.0f;
        W2p[threadIdx.x] = (threadIdx.x < HD) ? W2[threadIdx.x] : 0.0f;
    }
}

// ---- Kernel 2: fused T + MFMA conv-MLP + FIR lam1 + loglik partials ----
// T[k][t] = sum_j halpha[k][j]*obs[j][t] computed in-block (with 64-row halo);
// lam1[k][n] = softplus( sum_i beta*d^i * T[k][n-i] )  (FIR commutes with halpha map).
// __launch_bounds__(256,8): force <=64 VGPR so all 8 blocks/CU are co-resident (one round).
__global__ __launch_bounds__(256, 8)
void mlp_mfma_kernel(const float* __restrict__ covs, const float* __restrict__ obs,
                     const float* __restrict__ halpha, const float* __restrict__ hbeta,
                     const short* __restrict__ W1b, const float* __restrict__ b1p,
                     const float* __restrict__ W2p, const float* __restrict__ b2,
                     const float* __restrict__ gamma, float* __restrict__ lams,
                     float* __restrict__ partial) {
    __shared__ short cov_s[(NB + WIN) * MF];   // [320][8] bf16 rows, 16B each
    __shared__ float T_s[NB + WIN];            // T slice with left halo
    __shared__ float hsum[NB];
    __shared__ float wred[4];

    int k    = blockIdx.y;
    int n0   = blockIdx.x * NB;
    int tid  = threadIdx.x;
    int lane = tid & 63;
    int wave = tid >> 6;

    // ---- stage covs slice (edge-clamped) as bf16; rows 256..319 spread across waves ----
    const float* cbase = covs + (size_t)k * NT * MF;
    {
        int tt = n0 - DD + tid;                 // max n0+223 < NT always
        tt = tt < 0 ? 0 : tt;
        const float4* cp = (const float4*)(cbase + (size_t)tt * MF);
        float4 c0 = cp[0], c1 = cp[1];
        bf16x8 v;
        v[0] = f2bf(c0.x); v[1] = f2bf(c0.y); v[2] = f2bf(c0.z); v[3] = f2bf(c0.w);
        v[4] = f2bf(c1.x); v[5] = f2bf(c1.y); v[6] = f2bf(c1.z); v[7] = f2bf(c1.w);
        *(bf16x8*)&cov_s[tid * MF] = v;
    }
    if (lane < 16) {
        int rB = NB + wave * 16 + lane;         // rows 256..319
        int tt = n0 - DD + rB;                  // min n0+224 >= 0 always
        tt = tt > NT - 1 ? NT - 1 : tt;
        const float4* cp = (const float4*)(cbase + (size_t)tt * MF);
        float4 c0 = cp[0], c1 = cp[1];
        bf16x8 v;
        v[0] = f2bf(c0.x); v[1] = f2bf(c0.y); v[2] = f2bf(c0.z); v[3] = f2bf(c0.w);
        v[4] = f2bf(c1.x); v[5] = f2bf(c1.y); v[6] = f2bf(c1.z); v[7] = f2bf(c1.w);
        *(bf16x8*)&cov_s[rB * MF] = v;
    }

    // ---- fused T: T_s[r] = dot(halpha[k,:], obs[:, n0-WIN+r]), r = 0..319 ----
    // Row tid for all threads; rows 256..319 balanced 16-per-wave (computed by all
    // lanes for coalescing, stored by lanes 0..15).
    {
        const float* arow = halpha + (size_t)k * KL;   // wave-uniform -> s_load
        int tA = n0 - WIN + tid;
        tA = tA < 0 ? 0 : tA;                          // clamped rows guarded off in FIR
        int tB = n0 + (NB - WIN) + wave * 16 + lane;
        tB = tB > NT - 1 ? NT - 1 : tB;                // lanes>=16 discarded
        float aA = 0.0f, aB = 0.0f;
        #pragma unroll 8
        for (int j = 0; j < KL; ++j) {
            float aj = arow[j];
            const float* orow = obs + (size_t)j * NT;
            aA = fmaf(aj, orow[tA], aA);
            aB = fmaf(aj, orow[tB], aB);
        }
        T_s[tid] = aA;
        if (lane < 16) T_s[NB + wave * 16 + lane] = aB;
    }
    __syncthreads();

    int c = lane & 15;
    int g = lane >> 4;
    int wrow = wave * 64;

    f32x4 acc[4][2];
    #pragma unroll
    for (int mt = 0; mt < 4; ++mt) {
        acc[mt][0] = (f32x4){0.f, 0.f, 0.f, 0.f};
        acc[mt][1] = (f32x4){0.f, 0.f, 0.f, 0.f};
    }

    for (int kk = 0; kk < KF / 32; ++kk) {
        int f0 = kk * 32 + g * 8;
        bf16x8 b0  = *(const bf16x8*)&W1b[c * KF + f0];
        bf16x8 b1v = *(const bf16x8*)&W1b[(16 + c) * KF + f0];
        int d0 = kk * 4 + g;
        #pragma unroll
        for (int mt = 0; mt < 4; ++mt) {
            int t = wrow + mt * 16 + c + d0;
            bf16x8 a = *(const bf16x8*)&cov_s[t * MF];
            acc[mt][0] = __builtin_amdgcn_mfma_f32_16x16x32_bf16(a, b0,  acc[mt][0], 0, 0, 0);
            acc[mt][1] = __builtin_amdgcn_mfma_f32_16x16x32_bf16(a, b1v, acc[mt][1], 0, 0, 0);
        }
    }

    // epilogue: softplus + W2 dot, reduce over 16 col-lanes
    float w2a = W2p[c],      b1a = b1p[c];
    float w2b = W2p[16 + c], b1b = b1p[16 + c];
    #pragma unroll
    for (int mt = 0; mt < 4; ++mt) {
        float rs[4];
        #pragma unroll
        for (int j = 0; j < 4; ++j) {
            float v = w2a * softplus_f(acc[mt][0][j] + b1a)
                    + w2b * softplus_f(acc[mt][1][j] + b1b);
            v += __shfl_xor(v, 1, 64);
            v += __shfl_xor(v, 2, 64);
            v += __shfl_xor(v, 4, 64);
            v += __shfl_xor(v, 8, 64);
            rs[j] = v;
        }
        if (c == 0)
            *(float4*)&hsum[wrow + mt * 16 + g * 4] = (float4){rs[0], rs[1], rs[2], rs[3]};
    }
    __syncthreads();

    // lam1 via FIR on T_s (4 interleaved chains, decay^4 stride), then lam, loglik term
    int n = n0 + tid;
    float beta  = hbeta[0];
    float decay = __expf(-beta);
    int Lmax = (int)(88.0f / beta) + 2;        // beta=2 -> 46 taps
    float la = 0.0f;
    if (n0 > 0) {
        if (Lmax > WIN) Lmax = WIN;            // halo depth bound (i<=64 keeps idx>=tid)
        int it4 = (Lmax + 3) >> 2;             // extra taps have underflowed weights
        float d2 = decay * decay;
        float d4 = d2 * d2;
        float w1 = beta * decay, w2 = w1 * decay, w3 = w2 * decay, w4 = w3 * decay;
        float la0 = 0.f, la1 = 0.f, la2 = 0.f, la3 = 0.f;
        const float* Tp = &T_s[tid + WIN];
        for (int it = 0; it < it4; ++it) {
            int i = it * 4;
            la0 = fmaf(w1, Tp[-(i + 1)], la0); w1 *= d4;
            la1 = fmaf(w2, Tp[-(i + 2)], la1); w2 *= d4;
            la2 = fmaf(w3, Tp[-(i + 3)], la2); w3 *= d4;
            la3 = fmaf(w4, Tp[-(i + 4)], la3); w4 *= d4;
        }
        la = (la0 + la1) + (la2 + la3);
    } else {
        if (Lmax > NT) Lmax = NT;
        float w = beta * decay;
        for (int i = 1; i <= Lmax; ++i) {
            if (i <= n) la = fmaf(w, T_s[tid + WIN - i], la);
            w *= decay;
        }
    }
    float lam1 = softplus_f(la);
    float mu = softplus_f(hsum[tid] + b2[0]);
    size_t idx = (size_t)k * NT + n;
    float lam = lam1 + gamma[k] * mu;
    lams[idx] = lam;
    float term = fmaf(obs[idx], __logf(lam), -lam);

    #pragma unroll
    for (int off = 32; off > 0; off >>= 1) term += __shfl_down(term, off, 64);
    if ((tid & 63) == 0) wred[tid >> 6] = term;
    __syncthreads();
    if (tid == 0)
        partial[blockIdx.y * gridDim.x + blockIdx.x] =
            (wred[0] + wred[1]) + (wred[2] + wred[3]);
}

// ---- Kernel 3: sum 2048 per-block partials -> out[0] ----
__global__ __launch_bounds__(256)
void finalize_kernel(const float* __restrict__ partial, float* __restrict__ out0) {
    __shared__ float wred[4];
    int tid = threadIdx.x;
    float s = 0.0f;
    #pragma unroll
    for (int i = 0; i < NBLK / 256; ++i) s += partial[i * 256 + tid];
    #pragma unroll
    for (int off = 32; off > 0; off >>= 1) s += __shfl_down(s, off, 64);
    if ((tid & 63) == 0) wred[tid >> 6] = s;
    __syncthreads();
    if (tid == 0) out0[0] = (wred[0] + wred[1]) + (wred[2] + wred[3]);
}

extern "C" void kernel_launch(void* const* d_in, const int* in_sizes, int n_in,
                              void* d_out, int out_size, void* d_ws, size_t ws_size,
                              hipStream_t stream) {
    const float* obs    = (const float*)d_in[0];
    const float* covs   = (const float*)d_in[1];
    const float* hbeta  = (const float*)d_in[2];
    const float* halpha = (const float*)d_in[3];
    const float* gamma  = (const float*)d_in[4];
    const float* W1     = (const float*)d_in[5];
    const float* b1     = (const float*)d_in[6];
    const float* W2     = (const float*)d_in[7];
    const float* b2     = (const float*)d_in[8];

    float* out  = (float*)d_out;   // out[0]=loglik, out[1..]=lams [K][N]
    float* lams = out + 1;

    char* ws = (char*)d_ws;
    float* partial = (float*)ws;                 // 8 KB
    float* b1p     = (float*)(ws + 8192);        // 128 B
    float* W2p     = (float*)(ws + 8320);        // 128 B
    short* W1b     = (short*)(ws + 8448);        // 32 KB, 16B aligned

    dim3 block(256);
    pack_kernel<<<dim3(16), block, 0, stream>>>(W1, b1, W2, W1b, b1p, W2p);
    mlp_mfma_kernel<<<dim3(NXB, KL), block, 0, stream>>>(
        covs, obs, halpha, hbeta, W1b, b1p, W2p, b2, gamma, lams, partial);
    finalize_kernel<<<1, block, 0, stream>>>(partial, out);
}

// Round 2
// 74.861 us; speedup vs baseline: 1.4674x; 1.4674x over previous
//
#include <hip/hip_runtime.h>
#include <hip/hip_bf16.h>
#include <math.h>

#define KL 64      // locations
#define NT 8192    // time steps
#define MF 8       // covariate features
#define DD 32      // memory depth
#define WIN 64     // 2*DD window taps
#define HD 20      // hidden dim
#define HP 32      // hidden padded to 2 MFMA N-tiles
#define KF 512     // 2*DD*MF = GEMM K
#define NB 256     // n-rows per block
#define NXB (NT / NB)          // 32 n-tiles
#define NBLK (NXB * KL)        // 2048 mlp blocks

typedef __attribute__((ext_vector_type(8))) short bf16x8;
typedef __attribute__((ext_vector_type(4))) float f32x4;

// fast softplus: v_exp_f32 + v_log_f32
__device__ __forceinline__ float softplus_f(float x) {
    float e = __expf(-fabsf(x));
    return fmaxf(x, 0.0f) + __logf(1.0f + e);
}
__device__ __forceinline__ short f2bf(float x) {
    __hip_bfloat16 h = __float2bfloat16(x);
    return *reinterpret_cast<short*>(&h);
}

// ---- Kernel 1: T[k][n] = sum_j halpha[k][j]*obs[j][n]  (+ W1 bf16 pack in extra block) ----
// Uses: lam1[k][n] = softplus( sum_i beta*d^i * T[k][n-i] )  -- FIR commutes with halpha map.
__global__ __launch_bounds__(256)
void t_kernel(const float* __restrict__ obs, const float* __restrict__ halpha,
              const float* __restrict__ W1, const float* __restrict__ b1,
              const float* __restrict__ W2,
              float* __restrict__ T, short* __restrict__ W1b,
              float* __restrict__ b1p, float* __restrict__ W2p) {
    int k = blockIdx.y;
    if (blockIdx.x == NXB) {               // pack block
        if (k != 0) return;
        int t = threadIdx.x;
        for (int i = t; i < HP * KF; i += 256) {
            int o = i >> 9;                // KF = 512
            int f = i & (KF - 1);
            W1b[i] = (o < HD) ? f2bf(W1[o * KF + f]) : (short)0;
        }
        if (t < HP) {
            b1p[t] = (t < HD) ? b1[t] : 0.0f;
            W2p[t] = (t < HD) ? W2[t] : 0.0f;
        }
        return;
    }
    int n = blockIdx.x * 256 + threadIdx.x;
    const float* arow = halpha + k * KL;   // wave-uniform -> s_load
    float acc = 0.0f;
    #pragma unroll
    for (int j = 0; j < KL; ++j)
        acc = fmaf(arow[j], obs[(size_t)j * NT + n], acc);
    T[(size_t)k * NT + n] = acc;
}

// ---- Kernel 2: MFMA conv-MLP + FIR lam1 + loglik partials (no atomics) ----
// Two column-half passes (h=0: hidden 0..15, h=1: hidden 16..31) halve peak VGPR
// pressure in the kk loop (acc[4] instead of acc[4][2]) so all 8 blocks/CU are
// co-resident in one round (VGPR must stay <= 64; verify via counters).
__global__ __launch_bounds__(256)
void mlp_mfma_kernel(const float* __restrict__ covs, const float* __restrict__ obs,
                     const float* __restrict__ T, const float* __restrict__ hbeta,
                     const short* __restrict__ W1b, const float* __restrict__ b1p,
                     const float* __restrict__ W2p, const float* __restrict__ b2,
                     const float* __restrict__ gamma, float* __restrict__ lams,
                     float* __restrict__ partial) {
    __shared__ short cov_s[(NB + WIN) * MF];   // [320][8] bf16 rows, 16B each
    __shared__ float T_s[NB + WIN];            // T slice with left halo
    __shared__ float hsum[NB];
    __shared__ float wred[4];

    int k  = blockIdx.y;
    int n0 = blockIdx.x * NB;
    int tid = threadIdx.x;

    // stage covs slice (edge-clamped) as bf16, and T slice
    const float* cbase = covs + (size_t)k * NT * MF;
    const float* Trow  = T + (size_t)k * NT;
    for (int row = tid; row < NB + WIN; row += 256) {
        int tt = n0 - DD + row;
        tt = tt < 0 ? 0 : (tt > NT - 1 ? NT - 1 : tt);
        const float4* cp = (const float4*)(cbase + (size_t)tt * MF);
        float4 c0 = cp[0], c1 = cp[1];
        bf16x8 v;
        v[0] = f2bf(c0.x); v[1] = f2bf(c0.y); v[2] = f2bf(c0.z); v[3] = f2bf(c0.w);
        v[4] = f2bf(c1.x); v[5] = f2bf(c1.y); v[6] = f2bf(c1.z); v[7] = f2bf(c1.w);
        *(bf16x8*)&cov_s[row * MF] = v;
        int th = n0 - WIN + row;           // n0-64 .. n0+255
        T_s[row] = Trow[th < 0 ? 0 : th];  // clamped values are guarded off below
    }
    __syncthreads();

    int lane = tid & 63;
    int wave = tid >> 6;
    int c = lane & 15;
    int g = lane >> 4;
    int wrow = wave * 64;

    #pragma unroll
    for (int h = 0; h < 2; ++h) {
        f32x4 acc[4];
        #pragma unroll
        for (int mt = 0; mt < 4; ++mt) acc[mt] = (f32x4){0.f, 0.f, 0.f, 0.f};

        const short* Wh = W1b + (h * 16 + c) * KF;
        for (int kk = 0; kk < KF / 32; ++kk) {
            bf16x8 b = *(const bf16x8*)&Wh[kk * 32 + g * 8];
            int d0 = kk * 4 + g;
            #pragma unroll
            for (int mt = 0; mt < 4; ++mt) {
                bf16x8 a = *(const bf16x8*)&cov_s[(wrow + mt * 16 + c + d0) * MF];
                acc[mt] = __builtin_amdgcn_mfma_f32_16x16x32_bf16(a, b, acc[mt], 0, 0, 0);
            }
        }

        // epilogue: softplus + W2 dot, reduce over 16 col-lanes, accumulate hsum
        float w2 = W2p[h * 16 + c];
        float bb = b1p[h * 16 + c];
        #pragma unroll
        for (int mt = 0; mt < 4; ++mt) {
            float rs[4];
            #pragma unroll
            for (int j = 0; j < 4; ++j) {
                float v = w2 * softplus_f(acc[mt][j] + bb);
                v += __shfl_xor(v, 1, 64);
                v += __shfl_xor(v, 2, 64);
                v += __shfl_xor(v, 4, 64);
                v += __shfl_xor(v, 8, 64);
                rs[j] = v;
            }
            if (c == 0) {
                float4* hp = (float4*)&hsum[wrow + mt * 16 + g * 4];
                if (h == 0) {
                    *hp = (float4){rs[0], rs[1], rs[2], rs[3]};
                } else {
                    float4 o = *hp;
                    *hp = (float4){o.x + rs[0], o.y + rs[1], o.z + rs[2], o.w + rs[3]};
                }
            }
        }
    }
    __syncthreads();

    // lam1 via FIR on T_s (4 interleaved chains, decay^4 stride), then lam, loglik term
    int n = n0 + tid;
    float beta  = hbeta[0];
    float decay = __expf(-beta);
    int Lmax = (int)(88.0f / beta) + 2;        // beta=2 -> 46 taps
    float la = 0.0f;
    if (n0 > 0) {
        if (Lmax > WIN) Lmax = WIN;            // halo depth bound (i<=64 keeps idx>=tid)
        int it4 = (Lmax + 3) >> 2;             // extra taps have underflowed weights
        float d2 = decay * decay;
        float d4 = d2 * d2;
        float w1 = beta * decay, w2 = w1 * decay, w3 = w2 * decay, w4 = w3 * decay;
        float la0 = 0.f, la1 = 0.f, la2 = 0.f, la3 = 0.f;
        const float* Tp = &T_s[tid + WIN];
        for (int it = 0; it < it4; ++it) {
            int i = it * 4;
            la0 = fmaf(w1, Tp[-(i + 1)], la0); w1 *= d4;
            la1 = fmaf(w2, Tp[-(i + 2)], la1); w2 *= d4;
            la2 = fmaf(w3, Tp[-(i + 3)], la2); w3 *= d4;
            la3 = fmaf(w4, Tp[-(i + 4)], la3); w4 *= d4;
        }
        la = (la0 + la1) + (la2 + la3);
    } else {
        if (Lmax > NT) Lmax = NT;
        float w = beta * decay;
        for (int i = 1; i <= Lmax; ++i) {
            if (i <= n) la = fmaf(w, T_s[tid + WIN - i], la);
            w *= decay;
        }
    }
    float lam1 = softplus_f(la);
    float mu = softplus_f(hsum[tid] + b2[0]);
    size_t idx = (size_t)k * NT + n;
    float lam = lam1 + gamma[k] * mu;
    lams[idx] = lam;
    float term = fmaf(obs[idx], __logf(lam), -lam);

    #pragma unroll
    for (int off = 32; off > 0; off >>= 1) term += __shfl_down(term, off, 64);
    if ((tid & 63) == 0) wred[tid >> 6] = term;
    __syncthreads();
    if (tid == 0)
        partial[blockIdx.y * gridDim.x + blockIdx.x] =
            (wred[0] + wred[1]) + (wred[2] + wred[3]);
}

// ---- Kernel 3: sum 2048 per-block partials -> out[0] ----
__global__ __launch_bounds__(256)
void finalize_kernel(const float* __restrict__ partial, float* __restrict__ out0) {
    __shared__ float wred[4];
    int tid = threadIdx.x;
    float s = 0.0f;
    #pragma unroll
    for (int i = 0; i < NBLK / 256; ++i) s += partial[i * 256 + tid];
    #pragma unroll
    for (int off = 32; off > 0; off >>= 1) s += __shfl_down(s, off, 64);
    if ((tid & 63) == 0) wred[tid >> 6] = s;
    __syncthreads();
    if (tid == 0) out0[0] = (wred[0] + wred[1]) + (wred[2] + wred[3]);
}

extern "C" void kernel_launch(void* const* d_in, const int* in_sizes, int n_in,
                              void* d_out, int out_size, void* d_ws, size_t ws_size,
                              hipStream_t stream) {
    const float* obs    = (const float*)d_in[0];
    const float* covs   = (const float*)d_in[1];
    const float* hbeta  = (const float*)d_in[2];
    const float* halpha = (const float*)d_in[3];
    const float* gamma  = (const float*)d_in[4];
    const float* W1     = (const float*)d_in[5];
    const float* b1     = (const float*)d_in[6];
    const float* W2     = (const float*)d_in[7];
    const float* b2     = (const float*)d_in[8];

    float* out  = (float*)d_out;   // out[0]=loglik, out[1..]=lams [K][N]
    float* lams = out + 1;

    char* ws = (char*)d_ws;
    float* Tbuf    = (float*)ws;                                   // 2 MB
    float* partial = (float*)(ws + (size_t)KL * NT * 4);           // 8 KB
    float* b1p     = (float*)(ws + (size_t)KL * NT * 4 + 8192);    // 128 B
    float* W2p     = (float*)(ws + (size_t)KL * NT * 4 + 8320);    // 128 B
    short* W1b     = (short*)(ws + (size_t)KL * NT * 4 + 8448);    // 32 KB, 16B aligned

    dim3 block(256);
    t_kernel<<<dim3(NXB + 1, KL), block, 0, stream>>>(obs, halpha, W1, b1, W2,
                                                      Tbuf, W1b, b1p, W2p);
    mlp_mfma_kernel<<<dim3(NXB, KL), block, 0, stream>>>(
        covs, obs, Tbuf, hbeta, W1b, b1p, W2p, b2, gamma, lams, partial);
    finalize_kernel<<<1, block, 0, stream>>>(partial, out);
}

// Round 3
// 62.693 us; speedup vs baseline: 1.7522x; 1.1941x over previous
//
#include <hip/hip_runtime.h>
#include <hip/hip_bf16.h>
#include <math.h>

#define KL 64      // locations
#define NT 8192    // time steps
#define MF 8       // covariate features
#define DD 32      // memory depth
#define WIN 64     // 2*DD window taps
#define HD 20      // hidden dim
#define HP 32      // hidden padded to 2 MFMA N-tiles
#define KF 512     // 2*DD*MF = GEMM K
#define NB 256     // n-rows per block
#define NXB (NT / NB)          // 32 n-tiles
#define NBLK (NXB * KL)        // 2048 mlp blocks
#define GRPS (KF / 8)          // 64 fragment groups (kk*4+g)
#define GROW 21                // rows per group: 20 real + 1 zero row
#define W1SZ (GRPS * GROW * 8) // 10752 shorts = 21504 B

typedef __attribute__((ext_vector_type(8))) short bf16x8;
typedef __attribute__((ext_vector_type(4))) float f32x4;

// fast softplus: v_exp_f32 + v_log_f32
__device__ __forceinline__ float softplus_f(float x) {
    float e = __expf(-fabsf(x));
    return fmaxf(x, 0.0f) + __logf(1.0f + e);
}
__device__ __forceinline__ short f2bf(float x) {
    __hip_bfloat16 h = __float2bfloat16(x);
    return *reinterpret_cast<short*>(&h);
}

// ---- Kernel 1: T[k][n] = sum_j halpha[k][j]*obs[j][n]  (+ W1 fragment-pack block) ----
// W1 packed in MFMA-fragment order: W1b[(grp*GROW + r)*8 + e] = W1[r][grp*8 + e],
// r<HD real, r==HD zero row (for the c>=4 lanes of the second column tile).
__global__ __launch_bounds__(256)
void t_kernel(const float* __restrict__ obs, const float* __restrict__ halpha,
              const float* __restrict__ W1, const float* __restrict__ b1,
              const float* __restrict__ W2,
              float* __restrict__ T, short* __restrict__ W1b,
              float* __restrict__ b1p, float* __restrict__ W2p) {
    int k = blockIdx.y;
    if (blockIdx.x == NXB) {               // pack block
        if (k != 0) return;
        int t = threadIdx.x;
        for (int p = t; p < W1SZ; p += 256) {
            int e = p & 7;
            int rg = p >> 3;               // group-row index
            int r = rg % GROW;
            int grp = rg / GROW;           // 0..63 = kk*4 + g
            W1b[p] = (r < HD) ? f2bf(W1[r * KF + grp * 8 + e]) : (short)0;
        }
        if (t < HP) {
            b1p[t] = (t < HD) ? b1[t] : 0.0f;
            W2p[t] = (t < HD) ? W2[t] : 0.0f;
        }
        return;
    }
    int n = blockIdx.x * 256 + threadIdx.x;
    const float* arow = halpha + k * KL;   // wave-uniform -> s_load
    float acc = 0.0f;
    #pragma unroll
    for (int j = 0; j < KL; ++j)
        acc = fmaf(arow[j], obs[(size_t)j * NT + n], acc);
    T[(size_t)k * NT + n] = acc;
}

// ---- Kernel 2: MFMA conv-MLP + FIR lam1 + loglik partials (no atomics) ----
// B operand (W1) staged in LDS in fragment order: hot loop is 6 ds_read_b128 +
// 8 MFMA per kk with immediate offsets, zero global access, zero bank conflicts
// (16 c-lanes read contiguous 16B-stride rows; c>=4 second-tile reads broadcast
// the shared zero row).
__global__ __launch_bounds__(256)
void mlp_mfma_kernel(const float* __restrict__ covs, const float* __restrict__ obs,
                     const float* __restrict__ T, const float* __restrict__ hbeta,
                     const short* __restrict__ W1b, const float* __restrict__ b1p,
                     const float* __restrict__ W2p, const float* __restrict__ b2,
                     const float* __restrict__ gamma, float* __restrict__ lams,
                     float* __restrict__ partial) {
    __shared__ short cov_s[(NB + WIN) * MF];   // [320][8] bf16 rows, 16B each
    __shared__ short W1s[W1SZ];                // 21504 B fragment-ordered W1
    __shared__ float T_s[NB + WIN];            // T slice with left halo
    __shared__ float hsum[NB];
    __shared__ float wred[4];

    int k  = blockIdx.y;
    int n0 = blockIdx.x * NB;
    int tid = threadIdx.x;

    // stage W1 fragments: linear 21504 B copy (L2-hot, read-once per block)
    {
        const bf16x8* src = (const bf16x8*)W1b;
        bf16x8* dst = (bf16x8*)W1s;
        #pragma unroll
        for (int s = 0; s < 6; ++s) {
            int u = tid + s * 256;
            if (u < W1SZ / 8) dst[u] = src[u];
        }
    }

    // stage covs slice (edge-clamped) as bf16, and T slice
    const float* cbase = covs + (size_t)k * NT * MF;
    const float* Trow  = T + (size_t)k * NT;
    for (int row = tid; row < NB + WIN; row += 256) {
        int tt = n0 - DD + row;
        tt = tt < 0 ? 0 : (tt > NT - 1 ? NT - 1 : tt);
        const float4* cp = (const float4*)(cbase + (size_t)tt * MF);
        float4 c0 = cp[0], c1 = cp[1];
        bf16x8 v;
        v[0] = f2bf(c0.x); v[1] = f2bf(c0.y); v[2] = f2bf(c0.z); v[3] = f2bf(c0.w);
        v[4] = f2bf(c1.x); v[5] = f2bf(c1.y); v[6] = f2bf(c1.z); v[7] = f2bf(c1.w);
        *(bf16x8*)&cov_s[row * MF] = v;
        int th = n0 - WIN + row;           // n0-64 .. n0+255
        T_s[row] = Trow[th < 0 ? 0 : th];  // clamped values are guarded off below
    }
    __syncthreads();

    int lane = tid & 63;
    int wave = tid >> 6;
    int c = lane & 15;
    int g = lane >> 4;
    int wrow = wave * 64;

    f32x4 acc[4][2];
    #pragma unroll
    for (int mt = 0; mt < 4; ++mt) {
        acc[mt][0] = (f32x4){0.f, 0.f, 0.f, 0.f};
        acc[mt][1] = (f32x4){0.f, 0.f, 0.f, 0.f};
    }

    int r1 = 16 + c; r1 = r1 < HD ? r1 : HD;           // c>=4 -> zero row
    const short* pB0 = &W1s[g * (GROW * 8) + c * 8];
    const short* pB1 = &W1s[g * (GROW * 8) + r1 * 8];
    const short* pA  = &cov_s[(wrow + c + g) * MF];

    #pragma unroll
    for (int kk = 0; kk < KF / 32; ++kk) {
        bf16x8 b0  = *(const bf16x8*)(pB0 + kk * (4 * GROW * 8));
        bf16x8 b1v = *(const bf16x8*)(pB1 + kk * (4 * GROW * 8));
        #pragma unroll
        for (int mt = 0; mt < 4; ++mt) {
            bf16x8 a = *(const bf16x8*)(pA + (mt * 16 + kk * 4) * MF);
            acc[mt][0] = __builtin_amdgcn_mfma_f32_16x16x32_bf16(a, b0,  acc[mt][0], 0, 0, 0);
            acc[mt][1] = __builtin_amdgcn_mfma_f32_16x16x32_bf16(a, b1v, acc[mt][1], 0, 0, 0);
        }
    }

    // epilogue: softplus + W2 dot, reduce over 16 col-lanes
    float w2a = W2p[c],      b1a = b1p[c];
    float w2b = W2p[16 + c], b1b = b1p[16 + c];
    #pragma unroll
    for (int mt = 0; mt < 4; ++mt) {
        float rs[4];
        #pragma unroll
        for (int j = 0; j < 4; ++j) {
            float v = w2a * softplus_f(acc[mt][0][j] + b1a)
                    + w2b * softplus_f(acc[mt][1][j] + b1b);
            v += __shfl_xor(v, 1, 64);
            v += __shfl_xor(v, 2, 64);
            v += __shfl_xor(v, 4, 64);
            v += __shfl_xor(v, 8, 64);
            rs[j] = v;
        }
        if (c == 0)
            *(float4*)&hsum[wrow + mt * 16 + g * 4] = (float4){rs[0], rs[1], rs[2], rs[3]};
    }
    __syncthreads();

    // lam1 via FIR on T_s (4 interleaved chains, decay^4 stride), then lam, loglik term
    int n = n0 + tid;
    float beta  = hbeta[0];
    float decay = __expf(-beta);
    int Lmax = (int)(88.0f / beta) + 2;        // beta=2 -> 46 taps
    float la = 0.0f;
    if (n0 > 0) {
        if (Lmax > WIN) Lmax = WIN;            // halo depth bound (weights underflowed past it)
        int it4 = (Lmax + 3) >> 2;
        float d2 = decay * decay;
        float d4 = d2 * d2;
        float w1 = beta * decay, w2 = w1 * decay, w3 = w2 * decay, w4 = w3 * decay;
        float la0 = 0.f, la1 = 0.f, la2 = 0.f, la3 = 0.f;
        const float* Tp = &T_s[tid + WIN];
        for (int it = 0; it < it4; ++it) {
            int i = it * 4;
            la0 = fmaf(w1, Tp[-(i + 1)], la0); w1 *= d4;
            la1 = fmaf(w2, Tp[-(i + 2)], la1); w2 *= d4;
            la2 = fmaf(w3, Tp[-(i + 3)], la2); w3 *= d4;
            la3 = fmaf(w4, Tp[-(i + 4)], la3); w4 *= d4;
        }
        la = (la0 + la1) + (la2 + la3);
    } else {
        if (Lmax > NT) Lmax = NT;
        float w = beta * decay;
        for (int i = 1; i <= Lmax; ++i) {
            if (i <= n) la = fmaf(w, T_s[tid + WIN - i], la);
            w *= decay;
        }
    }
    float lam1 = softplus_f(la);
    float mu = softplus_f(hsum[tid] + b2[0]);
    size_t idx = (size_t)k * NT + n;
    float lam = lam1 + gamma[k] * mu;
    lams[idx] = lam;
    float term = fmaf(obs[idx], __logf(lam), -lam);

    #pragma unroll
    for (int off = 32; off > 0; off >>= 1) term += __shfl_down(term, off, 64);
    if ((tid & 63) == 0) wred[tid >> 6] = term;
    __syncthreads();
    if (tid == 0)
        partial[blockIdx.y * gridDim.x + blockIdx.x] =
            (wred[0] + wred[1]) + (wred[2] + wred[3]);
}

// ---- Kernel 3: sum 2048 per-block partials -> out[0] ----
__global__ __launch_bounds__(256)
void finalize_kernel(const float* __restrict__ partial, float* __restrict__ out0) {
    __shared__ float wred[4];
    int tid = threadIdx.x;
    float s = 0.0f;
    #pragma unroll
    for (int i = 0; i < NBLK / 256; ++i) s += partial[i * 256 + tid];
    #pragma unroll
    for (int off = 32; off > 0; off >>= 1) s += __shfl_down(s, off, 64);
    if ((tid & 63) == 0) wred[tid >> 6] = s;
    __syncthreads();
    if (tid == 0) out0[0] = (wred[0] + wred[1]) + (wred[2] + wred[3]);
}

extern "C" void kernel_launch(void* const* d_in, const int* in_sizes, int n_in,
                              void* d_out, int out_size, void* d_ws, size_t ws_size,
                              hipStream_t stream) {
    const float* obs    = (const float*)d_in[0];
    const float* covs   = (const float*)d_in[1];
    const float* hbeta  = (const float*)d_in[2];
    const float* halpha = (const float*)d_in[3];
    const float* gamma  = (const float*)d_in[4];
    const float* W1     = (const float*)d_in[5];
    const float* b1     = (const float*)d_in[6];
    const float* W2     = (const float*)d_in[7];
    const float* b2     = (const float*)d_in[8];

    float* out  = (float*)d_out;   // out[0]=loglik, out[1..]=lams [K][N]
    float* lams = out + 1;

    char* ws = (char*)d_ws;
    float* Tbuf    = (float*)ws;                                   // 2 MB
    float* partial = (float*)(ws + (size_t)KL * NT * 4);           // 8 KB
    float* b1p     = (float*)(ws + (size_t)KL * NT * 4 + 8192);    // 128 B
    float* W2p     = (float*)(ws + (size_t)KL * NT * 4 + 8320);    // 128 B
    short* W1b     = (short*)(ws + (size_t)KL * NT * 4 + 8448);    // 21.5 KB, 16B aligned

    dim3 block(256);
    t_kernel<<<dim3(NXB + 1, KL), block, 0, stream>>>(obs, halpha, W1, b1, W2,
                                                      Tbuf, W1b, b1p, W2p);
    mlp_mfma_kernel<<<dim3(NXB, KL), block, 0, stream>>>(
        covs, obs, Tbuf, hbeta, W1b, b1p, W2p, b2, gamma, lams, partial);
    finalize_kernel<<<1, block, 0, stream>>>(partial, out);
}

// Round 4
// 59.066 us; speedup vs baseline: 1.8598x; 1.0614x over previous
//
#include <hip/hip_runtime.h>
#include <hip/hip_bf16.h>
#include <math.h>

#define KL 64      // locations
#define NT 8192    // time steps
#define MF 8       // covariate features
#define DD 32      // memory depth
#define WIN 64     // 2*DD window taps
#define HD 20      // hidden dim
#define HP 32      // hidden padded to 2 MFMA N-tiles
#define KF 512     // 2*DD*MF = GEMM K
#define NB 256     // n-rows per block
#define NXB (NT / NB)          // 32 n-tiles
#define NBLK (NXB * KL)        // 2048 mlp blocks
#define GRPS (KF / 8)          // 64 fragment groups (kk*4+g)
#define GROW 21                // rows per group: 20 real + 1 zero row
#define W1SZ (GRPS * GROW * 8) // 10752 shorts = 21504 B

typedef __attribute__((ext_vector_type(8))) short bf16x8;
typedef __attribute__((ext_vector_type(4))) float f32x4;

// fast softplus: v_exp_f32 + v_log_f32
__device__ __forceinline__ float softplus_f(float x) {
    float e = __expf(-fabsf(x));
    return fmaxf(x, 0.0f) + __logf(1.0f + e);
}
__device__ __forceinline__ short f2bf(float x) {
    __hip_bfloat16 h = __float2bfloat16(x);
    return *reinterpret_cast<short*>(&h);
}

// ---- Kernel 1: T[k][n] = sum_j halpha[k][j]*obs[j][n]  (+ W1 fragment-pack block) ----
// W1 packed in MFMA-fragment order: W1b[(grp*GROW + r)*8 + e] = W1[r][grp*8 + e],
// r<HD real, r==HD zero row (for the c>=4 lanes of the second column tile).
__global__ __launch_bounds__(256)
void t_kernel(const float* __restrict__ obs, const float* __restrict__ halpha,
              const float* __restrict__ W1, const float* __restrict__ b1,
              const float* __restrict__ W2,
              float* __restrict__ T, short* __restrict__ W1b,
              float* __restrict__ b1p, float* __restrict__ W2p) {
    int k = blockIdx.y;
    if (blockIdx.x == NXB) {               // pack block
        if (k != 0) return;
        int t = threadIdx.x;
        for (int p = t; p < W1SZ; p += 256) {
            int e = p & 7;
            int rg = p >> 3;               // group-row index
            int r = rg % GROW;
            int grp = rg / GROW;           // 0..63 = kk*4 + g
            W1b[p] = (r < HD) ? f2bf(W1[r * KF + grp * 8 + e]) : (short)0;
        }
        if (t < HP) {
            b1p[t] = (t < HD) ? b1[t] : 0.0f;
            W2p[t] = (t < HD) ? W2[t] : 0.0f;
        }
        return;
    }
    int n = blockIdx.x * 256 + threadIdx.x;
    const float* arow = halpha + k * KL;   // wave-uniform -> s_load
    float acc = 0.0f;
    #pragma unroll
    for (int j = 0; j < KL; ++j)
        acc = fmaf(arow[j], obs[(size_t)j * NT + n], acc);
    T[(size_t)k * NT + n] = acc;
}

// ---- Kernel 2: MFMA conv-MLP + FIR lam1 + loglik partials (no atomics) ----
// B operand (W1) staged in LDS in fragment order. A fragments depend only on the
// diagonal s = 4*mt + kk (sliding window): rolling register buffer reads each of
// the 28 unique fragments ONCE (60 ds_read_b128/wave in the loop vs 96 naive).
__global__ __launch_bounds__(256)
void mlp_mfma_kernel(const float* __restrict__ covs, const float* __restrict__ obs,
                     const float* __restrict__ T, const float* __restrict__ hbeta,
                     const short* __restrict__ W1b, const float* __restrict__ b1p,
                     const float* __restrict__ W2p, const float* __restrict__ b2,
                     const float* __restrict__ gamma, float* __restrict__ lams,
                     float* __restrict__ partial) {
    __shared__ short cov_s[(NB + WIN) * MF];   // [320][8] bf16 rows, 16B each
    __shared__ short W1s[W1SZ];                // 21504 B fragment-ordered W1
    __shared__ float T_s[NB + WIN];            // T slice with left halo
    __shared__ float hsum[NB];
    __shared__ float wred[4];

    int k  = blockIdx.y;
    int n0 = blockIdx.x * NB;
    int tid = threadIdx.x;

    // stage W1 fragments: linear 21504 B copy (L2-hot, read-once per block)
    {
        const bf16x8* src = (const bf16x8*)W1b;
        bf16x8* dst = (bf16x8*)W1s;
        #pragma unroll
        for (int s = 0; s < 6; ++s) {
            int u = tid + s * 256;
            if (u < W1SZ / 8) dst[u] = src[u];
        }
    }

    // stage covs slice (edge-clamped) as bf16, and T slice
    const float* cbase = covs + (size_t)k * NT * MF;
    const float* Trow  = T + (size_t)k * NT;
    for (int row = tid; row < NB + WIN; row += 256) {
        int tt = n0 - DD + row;
        tt = tt < 0 ? 0 : (tt > NT - 1 ? NT - 1 : tt);
        const float4* cp = (const float4*)(cbase + (size_t)tt * MF);
        float4 c0 = cp[0], c1 = cp[1];
        bf16x8 v;
        v[0] = f2bf(c0.x); v[1] = f2bf(c0.y); v[2] = f2bf(c0.z); v[3] = f2bf(c0.w);
        v[4] = f2bf(c1.x); v[5] = f2bf(c1.y); v[6] = f2bf(c1.z); v[7] = f2bf(c1.w);
        *(bf16x8*)&cov_s[row * MF] = v;
        int th = n0 - WIN + row;           // n0-64 .. n0+255
        T_s[row] = Trow[th < 0 ? 0 : th];  // clamped values are guarded off below
    }
    __syncthreads();

    int lane = tid & 63;
    int wave = tid >> 6;
    int c = lane & 15;
    int g = lane >> 4;
    int wrow = wave * 64;

    f32x4 acc[4][2];
    #pragma unroll
    for (int mt = 0; mt < 4; ++mt) {
        acc[mt][0] = (f32x4){0.f, 0.f, 0.f, 0.f};
        acc[mt][1] = (f32x4){0.f, 0.f, 0.f, 0.f};
    }

    int r1 = 16 + c; r1 = r1 < HD ? r1 : HD;           // c>=4 -> zero row
    const short* pB0 = &W1s[g * (GROW * 8) + c * 8];
    const short* pB1 = &W1s[g * (GROW * 8) + r1 * 8];
    const short* pA  = &cov_s[(wrow + c + g) * MF];

    // rolling A-fragment buffer over the diagonal s = 4*mt + kk (28 unique frags)
    bf16x8 af[28];
    #pragma unroll
    for (int s = 0; s < 13; ++s)
        af[s] = *(const bf16x8*)(pA + s * 4 * MF);

    #pragma unroll
    for (int kk = 0; kk < KF / 32; ++kk) {
        if (kk < 15)
            af[kk + 13] = *(const bf16x8*)(pA + (kk + 13) * 4 * MF);
        bf16x8 b0  = *(const bf16x8*)(pB0 + kk * (4 * GROW * 8));
        bf16x8 b1v = *(const bf16x8*)(pB1 + kk * (4 * GROW * 8));
        #pragma unroll
        for (int mt = 0; mt < 4; ++mt) {
            bf16x8 a = af[kk + 4 * mt];
            acc[mt][0] = __builtin_amdgcn_mfma_f32_16x16x32_bf16(a, b0,  acc[mt][0], 0, 0, 0);
            acc[mt][1] = __builtin_amdgcn_mfma_f32_16x16x32_bf16(a, b1v, acc[mt][1], 0, 0, 0);
        }
    }

    // epilogue: softplus + W2 dot, reduce over 16 col-lanes
    float w2a = W2p[c],      b1a = b1p[c];
    float w2b = W2p[16 + c], b1b = b1p[16 + c];
    #pragma unroll
    for (int mt = 0; mt < 4; ++mt) {
        float rs[4];
        #pragma unroll
        for (int j = 0; j < 4; ++j) {
            float v = w2a * softplus_f(acc[mt][0][j] + b1a)
                    + w2b * softplus_f(acc[mt][1][j] + b1b);
            v += __shfl_xor(v, 1, 64);
            v += __shfl_xor(v, 2, 64);
            v += __shfl_xor(v, 4, 64);
            v += __shfl_xor(v, 8, 64);
            rs[j] = v;
        }
        if (c == 0)
            *(float4*)&hsum[wrow + mt * 16 + g * 4] = (float4){rs[0], rs[1], rs[2], rs[3]};
    }
    __syncthreads();

    // lam1 via FIR on T_s (4 interleaved chains, decay^4 stride), then lam, loglik.
    // Tap count: tail after L taps <= T*beta*e^{-beta(L+1)}/(1-e^{-beta}); T<=0.64,
    // so beta*L>=30 gives error ~1e-13 << tol. L = 30/beta+2 (=17 at beta=2).
    int n = n0 + tid;
    float beta  = hbeta[0];
    float decay = __expf(-beta);
    int Lmax = (int)(30.0f / beta) + 2;
    float la = 0.0f;
    if (n0 > 0) {
        if (Lmax > WIN) Lmax = WIN;            // halo depth bound
        int it4 = (Lmax + 3) >> 2;
        float d2 = decay * decay;
        float d4 = d2 * d2;
        float w1 = beta * decay, w2 = w1 * decay, w3 = w2 * decay, w4 = w3 * decay;
        float la0 = 0.f, la1 = 0.f, la2 = 0.f, la3 = 0.f;
        const float* Tp = &T_s[tid + WIN];
        for (int it = 0; it < it4; ++it) {
            int i = it * 4;
            la0 = fmaf(w1, Tp[-(i + 1)], la0); w1 *= d4;
            la1 = fmaf(w2, Tp[-(i + 2)], la1); w2 *= d4;
            la2 = fmaf(w3, Tp[-(i + 3)], la2); w3 *= d4;
            la3 = fmaf(w4, Tp[-(i + 4)], la3); w4 *= d4;
        }
        la = (la0 + la1) + (la2 + la3);
    } else {
        if (Lmax > NT) Lmax = NT;
        float w = beta * decay;
        for (int i = 1; i <= Lmax; ++i) {
            if (i <= n) la = fmaf(w, T_s[tid + WIN - i], la);
            w *= decay;
        }
    }
    float lam1 = softplus_f(la);
    float mu = softplus_f(hsum[tid] + b2[0]);
    size_t idx = (size_t)k * NT + n;
    float lam = lam1 + gamma[k] * mu;
    lams[idx] = lam;
    float term = fmaf(obs[idx], __logf(lam), -lam);

    #pragma unroll
    for (int off = 32; off > 0; off >>= 1) term += __shfl_down(term, off, 64);
    if ((tid & 63) == 0) wred[tid >> 6] = term;
    __syncthreads();
    if (tid == 0)
        partial[blockIdx.y * gridDim.x + blockIdx.x] =
            (wred[0] + wred[1]) + (wred[2] + wred[3]);
}

// ---- Kernel 3: sum 2048 per-block partials -> out[0] ----
__global__ __launch_bounds__(256)
void finalize_kernel(const float* __restrict__ partial, float* __restrict__ out0) {
    __shared__ float wred[4];
    int tid = threadIdx.x;
    float s = 0.0f;
    #pragma unroll
    for (int i = 0; i < NBLK / 256; ++i) s += partial[i * 256 + tid];
    #pragma unroll
    for (int off = 32; off > 0; off >>= 1) s += __shfl_down(s, off, 64);
    if ((tid & 63) == 0) wred[tid >> 6] = s;
    __syncthreads();
    if (tid == 0) out0[0] = (wred[0] + wred[1]) + (wred[2] + wred[3]);
}

extern "C" void kernel_launch(void* const* d_in, const int* in_sizes, int n_in,
                              void* d_out, int out_size, void* d_ws, size_t ws_size,
                              hipStream_t stream) {
    const float* obs    = (const float*)d_in[0];
    const float* covs   = (const float*)d_in[1];
    const float* hbeta  = (const float*)d_in[2];
    const float* halpha = (const float*)d_in[3];
    const float* gamma  = (const float*)d_in[4];
    const float* W1     = (const float*)d_in[5];
    const float* b1     = (const float*)d_in[6];
    const float* W2     = (const float*)d_in[7];
    const float* b2     = (const float*)d_in[8];

    float* out  = (float*)d_out;   // out[0]=loglik, out[1..]=lams [K][N]
    float* lams = out + 1;

    char* ws = (char*)d_ws;
    float* Tbuf    = (float*)ws;                                   // 2 MB
    float* partial = (float*)(ws + (size_t)KL * NT * 4);           // 8 KB
    float* b1p     = (float*)(ws + (size_t)KL * NT * 4 + 8192);    // 128 B
    float* W2p     = (float*)(ws + (size_t)KL * NT * 4 + 8320);    // 128 B
    short* W1b     = (short*)(ws + (size_t)KL * NT * 4 + 8448);    // 21.5 KB, 16B aligned

    dim3 block(256);
    t_kernel<<<dim3(NXB + 1, KL), block, 0, stream>>>(obs, halpha, W1, b1, W2,
                                                      Tbuf, W1b, b1p, W2p);
    mlp_mfma_kernel<<<dim3(NXB, KL), block, 0, stream>>>(
        covs, obs, Tbuf, hbeta, W1b, b1p, W2p, b2, gamma, lams, partial);
    finalize_kernel<<<1, block, 0, stream>>>(partial, out);
}

// Round 5
// 43.120 us; speedup vs baseline: 2.5475x; 1.3698x over previous
//
#include <hip/hip_runtime.h>
#include <hip/hip_bf16.h>
#include <math.h>

#define KL 64      // locations
#define NT 8192    // time steps
#define MF 8       // covariate features
#define DD 32      // memory depth
#define WIN 64     // 2*DD window taps
#define HD 20      // hidden dim
#define HP 32      // hidden padded to 2 MFMA N-tiles
#define KF 512     // 2*DD*MF = GEMM K
#define NB 256     // n-rows per block
#define NXB (NT / NB)          // 32 n-tiles
#define NBLK (NXB * KL)        // 2048 mlp blocks
#define GRPS (KF / 8)          // 64 fragment groups (kk*4+g)
#define GROW 24                // rows/group: 20 real + zero row 20 + pad (384B, line-aligned)
#define W1SZ (GRPS * GROW * 8) // 12288 shorts = 24576 B (fits 32KB L1)

typedef __attribute__((ext_vector_type(8))) short bf16x8;
typedef __attribute__((ext_vector_type(4))) float f32x4;

// fast softplus: v_exp_f32 + v_log_f32
__device__ __forceinline__ float softplus_f(float x) {
    float e = __expf(-fabsf(x));
    return fmaxf(x, 0.0f) + __logf(1.0f + e);
}
__device__ __forceinline__ short f2bf(float x) {
    __hip_bfloat16 h = __float2bfloat16(x);
    return *reinterpret_cast<short*>(&h);
}

// ---- Kernel 1 (tiny): pack W1 -> fragment-ordered bf16, pad b1/W2 ----
// W1b[(grp*GROW + r)*8 + e] = W1[r][grp*8 + e]; r<HD real, r>=HD zero.
__global__ __launch_bounds__(256)
void pack_kernel(const float* __restrict__ W1, const float* __restrict__ b1,
                 const float* __restrict__ W2, short* __restrict__ W1b,
                 float* __restrict__ b1p, float* __restrict__ W2p) {
    int t = blockIdx.x * 256 + threadIdx.x;      // grid 16 -> 4096 threads
    #pragma unroll
    for (int i = 0; i < 3; ++i) {
        int p = t + i * 4096;                    // W1SZ = 12288
        int e = p & 7;
        int rg = p >> 3;
        int r = rg % GROW;
        int grp = rg / GROW;                     // 0..63 = kk*4 + g
        W1b[p] = (r < HD) ? f2bf(W1[r * KF + grp * 8 + e]) : (short)0;
    }
    if (blockIdx.x == 0 && threadIdx.x < HP) {
        b1p[threadIdx.x] = (threadIdx.x < HD) ? b1[threadIdx.x] : 0.0f;
        W2p[threadIdx.x] = (threadIdx.x < HD) ? W2[threadIdx.x] : 0.0f;
    }
}

// ---- Kernel 2: fused T + MFMA conv-MLP (B from global/L1) + FIR lam1 + loglik ----
// T[k][t] = dot(halpha[k,:], obs[:,t]) computed in-block (FIR commutes with the
// halpha map). B-fragments read straight from the 24.5KB L1-resident packed W1b:
// per wave-load lanes hit 16 aligned 64B lines (c*16B within g, g stride 384B).
// LDS is only 7.7KB; target VGPR<=64 so all 8 blocks/CU are co-resident.
__global__ __launch_bounds__(256)
void mlp_mfma_kernel(const float* __restrict__ covs, const float* __restrict__ obs,
                     const float* __restrict__ halpha, const float* __restrict__ hbeta,
                     const short* __restrict__ W1b, const float* __restrict__ b1p,
                     const float* __restrict__ W2p, const float* __restrict__ b2,
                     const float* __restrict__ gamma, float* __restrict__ lams,
                     float* __restrict__ partial) {
    __shared__ short cov_s[(NB + WIN) * MF];   // [320][8] bf16 rows, 16B each
    __shared__ float T_s[NB + WIN];            // T slice with left halo
    __shared__ float hsum[NB];
    __shared__ float wred[4];

    int k    = blockIdx.y;
    int n0   = blockIdx.x * NB;
    int tid  = threadIdx.x;
    int lane = tid & 63;
    int wave = tid >> 6;

    // ---- stage covs slice (edge-clamped) as bf16 ----
    const float* cbase = covs + (size_t)k * NT * MF;
    for (int row = tid; row < NB + WIN; row += 256) {
        int tt = n0 - DD + row;
        tt = tt < 0 ? 0 : (tt > NT - 1 ? NT - 1 : tt);
        const float4* cp = (const float4*)(cbase + (size_t)tt * MF);
        float4 c0 = cp[0], c1 = cp[1];
        bf16x8 v;
        v[0] = f2bf(c0.x); v[1] = f2bf(c0.y); v[2] = f2bf(c0.z); v[3] = f2bf(c0.w);
        v[4] = f2bf(c1.x); v[5] = f2bf(c1.y); v[6] = f2bf(c1.z); v[7] = f2bf(c1.w);
        *(bf16x8*)&cov_s[row * MF] = v;
    }

    // ---- fused T: T_s[r] = dot(halpha[k,:], obs[:, n0-WIN+r]), r = 0..319 ----
    // rows 0..255 by tid; rows 256..319 computed by all lanes (coalescing),
    // stored by lanes 0..15 of each wave.
    {
        const float* arow = halpha + (size_t)k * KL;   // wave-uniform -> s_load
        int tA = n0 - WIN + tid;
        tA = tA < 0 ? 0 : tA;                          // clamped rows guarded in FIR
        int tB = n0 + (NB - WIN) + wave * 16 + (lane & 15);  // max 8191, in-bounds
        float aA = 0.0f, aB = 0.0f;
        #pragma unroll 8
        for (int j = 0; j < KL; ++j) {
            float aj = arow[j];
            const float* orow = obs + (size_t)j * NT;
            aA = fmaf(aj, orow[tA], aA);
            aB = fmaf(aj, orow[tB], aB);
        }
        T_s[tid] = aA;
        if (lane < 16) T_s[NB + wave * 16 + lane] = aB;
    }
    __syncthreads();

    int c = lane & 15;
    int g = lane >> 4;
    int wrow = wave * 64;

    f32x4 acc[4][2];
    #pragma unroll
    for (int mt = 0; mt < 4; ++mt) {
        acc[mt][0] = (f32x4){0.f, 0.f, 0.f, 0.f};
        acc[mt][1] = (f32x4){0.f, 0.f, 0.f, 0.f};
    }

    int r1 = (c < 4) ? (16 + c) : HD;                  // c>=4 -> zero row 20
    const short* pB0 = W1b + g * (GROW * 8) + c * 8;
    const short* pB1 = W1b + g * (GROW * 8) + r1 * 8;
    const short* pA  = &cov_s[(wrow + c + g) * MF];

    #pragma unroll 2
    for (int kk = 0; kk < KF / 32; ++kk) {
        bf16x8 b0  = *(const bf16x8*)(pB0 + kk * (4 * GROW * 8));
        bf16x8 b1v = *(const bf16x8*)(pB1 + kk * (4 * GROW * 8));
        #pragma unroll
        for (int mt = 0; mt < 4; ++mt) {
            bf16x8 a = *(const bf16x8*)(pA + (mt * 16 + kk * 4) * MF);
            acc[mt][0] = __builtin_amdgcn_mfma_f32_16x16x32_bf16(a, b0,  acc[mt][0], 0, 0, 0);
            acc[mt][1] = __builtin_amdgcn_mfma_f32_16x16x32_bf16(a, b1v, acc[mt][1], 0, 0, 0);
        }
    }

    // epilogue: softplus + W2 dot, reduce over 16 col-lanes
    float w2a = W2p[c],      b1a = b1p[c];
    float w2b = W2p[16 + c], b1b = b1p[16 + c];
    #pragma unroll
    for (int mt = 0; mt < 4; ++mt) {
        float rs[4];
        #pragma unroll
        for (int j = 0; j < 4; ++j) {
            float v = w2a * softplus_f(acc[mt][0][j] + b1a)
                    + w2b * softplus_f(acc[mt][1][j] + b1b);
            v += __shfl_xor(v, 1, 64);
            v += __shfl_xor(v, 2, 64);
            v += __shfl_xor(v, 4, 64);
            v += __shfl_xor(v, 8, 64);
            rs[j] = v;
        }
        if (c == 0)
            *(float4*)&hsum[wrow + mt * 16 + g * 4] = (float4){rs[0], rs[1], rs[2], rs[3]};
    }
    __syncthreads();

    // lam1 via FIR on T_s (4 interleaved chains, decay^4 stride), then lam, loglik.
    // Taps: tail after L <= T*beta*e^{-beta(L+1)}/(1-e^{-beta}), T<=0.64 ->
    // beta*L>=30 gives ~1e-13 error. L = 30/beta+2 (=17 at beta=2).
    int n = n0 + tid;
    float beta  = hbeta[0];
    float decay = __expf(-beta);
    int Lmax = (int)(30.0f / beta) + 2;
    float la = 0.0f;
    if (n0 > 0) {
        if (Lmax > WIN) Lmax = WIN;            // halo depth bound
        int it4 = (Lmax + 3) >> 2;
        float d2 = decay * decay;
        float d4 = d2 * d2;
        float w1 = beta * decay, w2 = w1 * decay, w3 = w2 * decay, w4 = w3 * decay;
        float la0 = 0.f, la1 = 0.f, la2 = 0.f, la3 = 0.f;
        const float* Tp = &T_s[tid + WIN];
        for (int it = 0; it < it4; ++it) {
            int i = it * 4;
            la0 = fmaf(w1, Tp[-(i + 1)], la0); w1 *= d4;
            la1 = fmaf(w2, Tp[-(i + 2)], la1); w2 *= d4;
            la2 = fmaf(w3, Tp[-(i + 3)], la2); w3 *= d4;
            la3 = fmaf(w4, Tp[-(i + 4)], la3); w4 *= d4;
        }
        la = (la0 + la1) + (la2 + la3);
    } else {
        if (Lmax > NT) Lmax = NT;
        float w = beta * decay;
        for (int i = 1; i <= Lmax; ++i) {
            if (i <= n) la = fmaf(w, T_s[tid + WIN - i], la);
            w *= decay;
        }
    }
    float lam1 = softplus_f(la);
    float mu = softplus_f(hsum[tid] + b2[0]);
    size_t idx = (size_t)k * NT + n;
    float lam = lam1 + gamma[k] * mu;
    lams[idx] = lam;
    float term = fmaf(obs[idx], __logf(lam), -lam);

    #pragma unroll
    for (int off = 32; off > 0; off >>= 1) term += __shfl_down(term, off, 64);
    if ((tid & 63) == 0) wred[tid >> 6] = term;
    __syncthreads();
    if (tid == 0)
        partial[blockIdx.y * gridDim.x + blockIdx.x] =
            (wred[0] + wred[1]) + (wred[2] + wred[3]);
}

// ---- Kernel 3: sum 2048 per-block partials -> out[0] ----
__global__ __launch_bounds__(256)
void finalize_kernel(const float* __restrict__ partial, float* __restrict__ out0) {
    __shared__ float wred[4];
    int tid = threadIdx.x;
    float s = 0.0f;
    #pragma unroll
    for (int i = 0; i < NBLK / 256; ++i) s += partial[i * 256 + tid];
    #pragma unroll
    for (int off = 32; off > 0; off >>= 1) s += __shfl_down(s, off, 64);
    if ((tid & 63) == 0) wred[tid >> 6] = s;
    __syncthreads();
    if (tid == 0) out0[0] = (wred[0] + wred[1]) + (wred[2] + wred[3]);
}

extern "C" void kernel_launch(void* const* d_in, const int* in_sizes, int n_in,
                              void* d_out, int out_size, void* d_ws, size_t ws_size,
                              hipStream_t stream) {
    const float* obs    = (const float*)d_in[0];
    const float* covs   = (const float*)d_in[1];
    const float* hbeta  = (const float*)d_in[2];
    const float* halpha = (const float*)d_in[3];
    const float* gamma  = (const float*)d_in[4];
    const float* W1     = (const float*)d_in[5];
    const float* b1     = (const float*)d_in[6];
    const float* W2     = (const float*)d_in[7];
    const float* b2     = (const float*)d_in[8];

    float* out  = (float*)d_out;   // out[0]=loglik, out[1..]=lams [K][N]
    float* lams = out + 1;

    char* ws = (char*)d_ws;
    float* partial = (float*)ws;                 // 8 KB
    float* b1p     = (float*)(ws + 8192);        // 128 B
    float* W2p     = (float*)(ws + 8320);        // 128 B
    short* W1b     = (short*)(ws + 8448);        // 24.5 KB, 16B aligned

    dim3 block(256);
    pack_kernel<<<dim3(16), block, 0, stream>>>(W1, b1, W2, W1b, b1p, W2p);
    mlp_mfma_kernel<<<dim3(NXB, KL), block, 0, stream>>>(
        covs, obs, halpha, hbeta, W1b, b1p, W2p, b2, gamma, lams, partial);
    finalize_kernel<<<1, block, 0, stream>>>(partial, out);
}

// Round 6
// 42.672 us; speedup vs baseline: 2.5742x; 1.0105x over previous
//
#include <hip/hip_runtime.h>
#include <hip/hip_bf16.h>
#include <math.h>

#define KL 64      // locations
#define NT 8192    // time steps
#define MF 8       // covariate features
#define DD 32      // memory depth
#define WIN 64     // 2*DD window taps
#define HD 20      // hidden dim
#define HP 32      // hidden padded to 2 MFMA N-tiles
#define KF 512     // 2*DD*MF = GEMM K
#define NB 256     // n-rows per block
#define NXB (NT / NB)          // 32 n-tiles
#define NBLK (NXB * KL)        // 2048 mlp blocks
#define GRPS (KF / 8)          // 64 fragment groups (kk*4+g)
#define GROW 24                // rows/group: 20 real + zero row 20 + pad (384B, line-aligned)
#define W1SZ (GRPS * GROW * 8) // 12288 shorts = 24576 B (fits 32KB L1)

typedef __attribute__((ext_vector_type(8))) short bf16x8;
typedef __attribute__((ext_vector_type(4))) float f32x4;

// fast softplus: v_exp_f32 + v_log_f32
__device__ __forceinline__ float softplus_f(float x) {
    float e = __expf(-fabsf(x));
    return fmaxf(x, 0.0f) + __logf(1.0f + e);
}
__device__ __forceinline__ short f2bf(float x) {
    __hip_bfloat16 h = __float2bfloat16(x);
    return *reinterpret_cast<short*>(&h);
}

// ---- Kernel 1 (tiny): pack W1 -> fragment-ordered bf16, pad b1/W2 ----
// W1b[(grp*GROW + r)*8 + e] = W1[r][grp*8 + e]; r<HD real, r>=HD zero.
__global__ __launch_bounds__(256)
void pack_kernel(const float* __restrict__ W1, const float* __restrict__ b1,
                 const float* __restrict__ W2, short* __restrict__ W1b,
                 float* __restrict__ b1p, float* __restrict__ W2p) {
    int t = blockIdx.x * 256 + threadIdx.x;      // grid 16 -> 4096 threads
    #pragma unroll
    for (int i = 0; i < 3; ++i) {
        int p = t + i * 4096;                    // W1SZ = 12288
        int e = p & 7;
        int rg = p >> 3;
        int r = rg % GROW;
        int grp = rg / GROW;                     // 0..63 = kk*4 + g
        W1b[p] = (r < HD) ? f2bf(W1[r * KF + grp * 8 + e]) : (short)0;
    }
    if (blockIdx.x == 0 && threadIdx.x < HP) {
        b1p[threadIdx.x] = (threadIdx.x < HD) ? b1[threadIdx.x] : 0.0f;
        W2p[threadIdx.x] = (threadIdx.x < HD) ? W2[threadIdx.x] : 0.0f;
    }
}

// ---- Kernel 2: fused T + MFMA conv-MLP + FIR lam1 + loglik partials ----
// The T-dot (T[k][t] = dot(halpha[k,:], obs[:,t])) is INTERLEAVED into the MFMA
// kk-loop, 4 j-steps per iteration: its global-load latency hides under the
// 8 MFMAs + A/B reads of each iteration instead of being an exposed serial
// phase. B-fragments come from the 24.5KB L1-resident packed W1b.
__global__ __launch_bounds__(256)
void mlp_mfma_kernel(const float* __restrict__ covs, const float* __restrict__ obs,
                     const float* __restrict__ halpha, const float* __restrict__ hbeta,
                     const short* __restrict__ W1b, const float* __restrict__ b1p,
                     const float* __restrict__ W2p, const float* __restrict__ b2,
                     const float* __restrict__ gamma, float* __restrict__ lams,
                     float* __restrict__ partial) {
    __shared__ short cov_s[(NB + WIN) * MF];   // [320][8] bf16 rows, 16B each
    __shared__ float T_s[NB + WIN];            // T slice with left halo
    __shared__ float hsum[NB];
    __shared__ float wred[4];

    int k    = blockIdx.y;
    int n0   = blockIdx.x * NB;
    int tid  = threadIdx.x;
    int lane = tid & 63;
    int wave = tid >> 6;

    // hoist tail-section scalars/loads: latency hides under staging + GEMM
    int n = n0 + tid;
    size_t idx = (size_t)k * NT + n;
    float obs_n = obs[idx];
    float beta  = hbeta[0];
    float gam   = gamma[k];
    float b2v   = b2[0];

    // ---- stage covs slice (edge-clamped) as bf16 ----
    const float* cbase = covs + (size_t)k * NT * MF;
    for (int row = tid; row < NB + WIN; row += 256) {
        int tt = n0 - DD + row;
        tt = tt < 0 ? 0 : (tt > NT - 1 ? NT - 1 : tt);
        const float4* cp = (const float4*)(cbase + (size_t)tt * MF);
        float4 c0 = cp[0], c1 = cp[1];
        bf16x8 v;
        v[0] = f2bf(c0.x); v[1] = f2bf(c0.y); v[2] = f2bf(c0.z); v[3] = f2bf(c0.w);
        v[4] = f2bf(c1.x); v[5] = f2bf(c1.y); v[6] = f2bf(c1.z); v[7] = f2bf(c1.w);
        *(bf16x8*)&cov_s[row * MF] = v;
    }
    __syncthreads();

    int c = lane & 15;
    int g = lane >> 4;
    int wrow = wave * 64;

    f32x4 acc[4][2];
    #pragma unroll
    for (int mt = 0; mt < 4; ++mt) {
        acc[mt][0] = (f32x4){0.f, 0.f, 0.f, 0.f};
        acc[mt][1] = (f32x4){0.f, 0.f, 0.f, 0.f};
    }

    int r1 = (c < 4) ? (16 + c) : HD;                  // c>=4 -> zero row 20
    const short* pB0 = W1b + g * (GROW * 8) + c * 8;
    const short* pB1 = W1b + g * (GROW * 8) + r1 * 8;
    const short* pA  = &cov_s[(wrow + c + g) * MF];

    // T-dot state: T_s[tid] = dot over cols n0-64+tid; halo cols n0+192..255
    // computed by lanes' (lane&15) pattern (stored by lanes 0..15 per wave).
    const float* arow = halpha + (size_t)k * KL;       // wave-uniform -> s_load
    int tA = n0 - WIN + tid;
    tA = tA < 0 ? 0 : tA;                              // clamped rows guarded in FIR
    int tB = n0 + (NB - WIN) + wave * 16 + (lane & 15);  // max 8191, in-bounds
    float aA = 0.0f, aB = 0.0f;

    #pragma unroll 2
    for (int kk = 0; kk < KF / 32; ++kk) {
        // 4 T j-steps interleaved with this kk's MFMA work
        #pragma unroll
        for (int jj = 0; jj < 4; ++jj) {
            int j = kk * 4 + jj;
            float aj = arow[j];
            const float* orow = obs + (size_t)j * NT;
            aA = fmaf(aj, orow[tA], aA);
            aB = fmaf(aj, orow[tB], aB);
        }
        bf16x8 b0  = *(const bf16x8*)(pB0 + kk * (4 * GROW * 8));
        bf16x8 b1v = *(const bf16x8*)(pB1 + kk * (4 * GROW * 8));
        #pragma unroll
        for (int mt = 0; mt < 4; ++mt) {
            bf16x8 a = *(const bf16x8*)(pA + (mt * 16 + kk * 4) * MF);
            acc[mt][0] = __builtin_amdgcn_mfma_f32_16x16x32_bf16(a, b0,  acc[mt][0], 0, 0, 0);
            acc[mt][1] = __builtin_amdgcn_mfma_f32_16x16x32_bf16(a, b1v, acc[mt][1], 0, 0, 0);
        }
    }
    T_s[tid] = aA;
    if (lane < 16) T_s[NB + wave * 16 + lane] = aB;

    // epilogue: softplus + W2 dot, reduce over 16 col-lanes
    float w2a = W2p[c],      b1a = b1p[c];
    float w2b = W2p[16 + c], b1b = b1p[16 + c];
    #pragma unroll
    for (int mt = 0; mt < 4; ++mt) {
        float rs[4];
        #pragma unroll
        for (int j = 0; j < 4; ++j) {
            float v = w2a * softplus_f(acc[mt][0][j] + b1a)
                    + w2b * softplus_f(acc[mt][1][j] + b1b);
            v += __shfl_xor(v, 1, 64);
            v += __shfl_xor(v, 2, 64);
            v += __shfl_xor(v, 4, 64);
            v += __shfl_xor(v, 8, 64);
            rs[j] = v;
        }
        if (c == 0)
            *(float4*)&hsum[wrow + mt * 16 + g * 4] = (float4){rs[0], rs[1], rs[2], rs[3]};
    }
    __syncthreads();

    // lam1 via FIR on T_s (4 interleaved chains, decay^4 stride), then lam, loglik.
    // Taps: tail after L <= T*beta*e^{-beta(L+1)}/(1-e^{-beta}), T<=0.64 ->
    // beta*L>=30 gives ~1e-13 error. L = 30/beta+2 (=17 at beta=2).
    float decay = __expf(-beta);
    int Lmax = (int)(30.0f / beta) + 2;
    float la = 0.0f;
    if (n0 > 0) {
        if (Lmax > WIN) Lmax = WIN;            // halo depth bound
        int it4 = (Lmax + 3) >> 2;
        float d2 = decay * decay;
        float d4 = d2 * d2;
        float w1 = beta * decay, w2 = w1 * decay, w3 = w2 * decay, w4 = w3 * decay;
        float la0 = 0.f, la1 = 0.f, la2 = 0.f, la3 = 0.f;
        const float* Tp = &T_s[tid + WIN];
        for (int it = 0; it < it4; ++it) {
            int i = it * 4;
            la0 = fmaf(w1, Tp[-(i + 1)], la0); w1 *= d4;
            la1 = fmaf(w2, Tp[-(i + 2)], la1); w2 *= d4;
            la2 = fmaf(w3, Tp[-(i + 3)], la2); w3 *= d4;
            la3 = fmaf(w4, Tp[-(i + 4)], la3); w4 *= d4;
        }
        la = (la0 + la1) + (la2 + la3);
    } else {
        if (Lmax > NT) Lmax = NT;
        float w = beta * decay;
        for (int i = 1; i <= Lmax; ++i) {
            if (i <= n) la = fmaf(w, T_s[tid + WIN - i], la);
            w *= decay;
        }
    }
    float lam1 = softplus_f(la);
    float mu = softplus_f(hsum[tid] + b2v);
    float lam = lam1 + gam * mu;
    lams[idx] = lam;
    float term = fmaf(obs_n, __logf(lam), -lam);

    #pragma unroll
    for (int off = 32; off > 0; off >>= 1) term += __shfl_down(term, off, 64);
    if ((tid & 63) == 0) wred[tid >> 6] = term;
    __syncthreads();
    if (tid == 0)
        partial[blockIdx.y * gridDim.x + blockIdx.x] =
            (wred[0] + wred[1]) + (wred[2] + wred[3]);
}

// ---- Kernel 3: sum 2048 per-block partials -> out[0] ----
__global__ __launch_bounds__(256)
void finalize_kernel(const float* __restrict__ partial, float* __restrict__ out0) {
    __shared__ float wred[4];
    int tid = threadIdx.x;
    float s = 0.0f;
    #pragma unroll
    for (int i = 0; i < NBLK / 256; ++i) s += partial[i * 256 + tid];
    #pragma unroll
    for (int off = 32; off > 0; off >>= 1) s += __shfl_down(s, off, 64);
    if ((tid & 63) == 0) wred[tid >> 6] = s;
    __syncthreads();
    if (tid == 0) out0[0] = (wred[0] + wred[1]) + (wred[2] + wred[3]);
}

extern "C" void kernel_launch(void* const* d_in, const int* in_sizes, int n_in,
                              void* d_out, int out_size, void* d_ws, size_t ws_size,
                              hipStream_t stream) {
    const float* obs    = (const float*)d_in[0];
    const float* covs   = (const float*)d_in[1];
    const float* hbeta  = (const float*)d_in[2];
    const float* halpha = (const float*)d_in[3];
    const float* gamma  = (const float*)d_in[4];
    const float* W1     = (const float*)d_in[5];
    const float* b1     = (const float*)d_in[6];
    const float* W2     = (const float*)d_in[7];
    const float* b2     = (const float*)d_in[8];

    float* out  = (float*)d_out;   // out[0]=loglik, out[1..]=lams [K][N]
    float* lams = out + 1;

    char* ws = (char*)d_ws;
    float* partial = (float*)ws;                 // 8 KB
    float* b1p     = (float*)(ws + 8192);        // 128 B
    float* W2p     = (float*)(ws + 8320);        // 128 B
    short* W1b     = (short*)(ws + 8448);        // 24.5 KB, 16B aligned

    dim3 block(256);
    pack_kernel<<<dim3(16), block, 0, stream>>>(W1, b1, W2, W1b, b1p, W2p);
    mlp_mfma_kernel<<<dim3(NXB, KL), block, 0, stream>>>(
        covs, obs, halpha, hbeta, W1b, b1p, W2p, b2, gamma, lams, partial);
    finalize_kernel<<<1, block, 0, stream>>>(partial, out);
}